// Round 3
// baseline (139.502 us; speedup 1.0000x reference)
//
#include <hip/hip_runtime.h>
#include <math.h>

#define NP   261121   // 511*511
#define WPX  520      // padded pixel row stride (rows 0..513, interior cols 1..511)
#define ROWN 4160     // WPX*8 ushorts per plane-row
#define PSTR 2138240  // 514*ROWN ushorts per channel-group plane

typedef __attribute__((ext_vector_type(8))) short short8;
typedef __attribute__((ext_vector_type(4))) float f32x4;

static __device__ __forceinline__ unsigned short f2bf(float f) {
    unsigned int u = __builtin_bit_cast(unsigned int, f);
    u += 0x7FFFu + ((u >> 16) & 1u);   // round-to-nearest-even
    return (unsigned short)(u >> 16);
}

// ---------------- K0: weight prep + h2 pad-ring zero ------------------------
// wTa[k*32+o] = w_c9a[o*9+k]
// wT1[c*16+o] = w_x1[o*204+c]
// wb2[k*2048 + o*32 + c] = bf16(w_c9b[o*288 + c*9 + k])
__global__ __launch_bounds__(256) void k_prep(const float* __restrict__ w_c9a,
                                              const float* __restrict__ w_c9b,
                                              const float* __restrict__ w_x1,
                                              float* __restrict__ wTa,
                                              unsigned short* __restrict__ wb2,
                                              float* __restrict__ wT1,
                                              unsigned short* __restrict__ h2)
{
    int t = blockIdx.x * 256 + threadIdx.x;
    if (t < 288)  wTa[t] = w_c9a[(t & 31) * 9 + (t >> 5)];
    if (t < 3264) wT1[t] = w_x1[(t & 15) * 204 + (t >> 4)];
    if (t < 18432) {
        int o = t / 288, ck = t - o * 288;
        int c = ck / 9, k = ck - c * 9;
        wb2[k * 2048 + o * 32 + c] = f2bf(w_c9b[t]);
    }
    short8 z8 = {0, 0, 0, 0, 0, 0, 0, 0};
    // region A: full rows 0 and 512 in all 4 planes: 2*4*520 = 4160 chunks of 16B
    if (t < 4160) {
        int pl = t / 1040;
        int rr = t - pl * 1040;
        int row = rr >= 520 ? 512 : 0;
        int ch  = rr >= 520 ? rr - 520 : rr;
        *reinterpret_cast<short8*>(h2 + (size_t)pl * PSTR + (size_t)row * ROWN + ch * 8) = z8;
    }
    // region B: rows 1..511, cols {0,512,513}, all planes: 511*12 = 6132 chunks
    int z = t - 4160;
    if (z >= 0 && z < 6132) {
        int row = z / 12 + 1;
        int j = z - (row - 1) * 12;
        int pl = j / 3, cidx = j - pl * 3;
        int col = (cidx == 0) ? 0 : (cidx == 1 ? 512 : 513);
        *reinterpret_cast<short8*>(h2 + (size_t)pl * PSTR + (size_t)row * ROWN + col * 8) = z8;
    }
}

// ---------------- K1: fused 1x1 convs 204->16->8->1 (relu each) -------------
// Weights read through wave-uniform addresses -> scalar loads (no LDS).
__global__ __launch_bounds__(256) void k_conv123(const float* __restrict__ x,
                                                 const float* __restrict__ wT1,
                                                 const float* __restrict__ b1,
                                                 const float* __restrict__ w2,
                                                 const float* __restrict__ b2,
                                                 const float* __restrict__ w3,
                                                 const float* __restrict__ b3,
                                                 float* __restrict__ tmp12)
{
    int p0 = blockIdx.x * 256 + threadIdx.x;
    int p = p0 < NP ? p0 : NP - 1;

    float acc[16];
#pragma unroll
    for (int o = 0; o < 16; ++o) acc[o] = 0.f;

    const float* xp = x + p;
#pragma unroll 2
    for (int c = 0; c < 204; ++c) {
        float xv = xp[c * NP];
        const float* wp = wT1 + c * 16;   // uniform -> s_load
#pragma unroll
        for (int o = 0; o < 16; ++o) acc[o] = fmaf(xv, wp[o], acc[o]);
    }

    float f1[16];
#pragma unroll
    for (int o = 0; o < 16; ++o) f1[o] = fmaxf(acc[o] + b1[o], 0.f);

    float tmp = b3[0];
#pragma unroll
    for (int j = 0; j < 8; ++j) {
        float s = b2[j];
#pragma unroll
        for (int o = 0; o < 16; ++o) s = fmaf(f1[o], w2[j * 16 + o], s);
        tmp = fmaf(fmaxf(s, 0.f), w3[j], tmp);
    }
    if (p0 < NP) tmp12[p0] = fmaxf(tmp, 0.f);
}

// ------------- K2: Haar DWT (zero-pad) + 1x1 conv(pad=1) + pixel_shuffle ----
__global__ __launch_bounds__(256) void k_dwt_hi(const float* __restrict__ tmp12,
                                                const float* __restrict__ w_hi,
                                                const float* __restrict__ b_hi,
                                                float* __restrict__ hf)
{
    const float INV = 0.70710678118654752440f;
    int idx = blockIdx.x * 256 + threadIdx.x;
    if (idx >= 258 * 258) return;
    int h = idx / 258, w = idx - h * 258;

    float wh[12], bh[4];
#pragma unroll
    for (int i = 0; i < 12; ++i) wh[i] = w_hi[i];
#pragma unroll
    for (int o = 0; o < 4; ++o) bh[o] = b_hi[o];

    float v[4];
    if (h == 0 || h == 257 || w == 0 || w == 257) {
#pragma unroll
        for (int o = 0; o < 4; ++o) v[o] = fmaxf(bh[o], 0.f);
    } else {
        int hh = h - 1, ww = w - 1;
        int r0 = 2 * hh, r1 = 2 * hh + 1, c0 = 2 * ww, c1 = 2 * ww + 1;
        float a = tmp12[r0 * 511 + c0];
        float b = (c1 < 511) ? tmp12[r0 * 511 + c1] : 0.f;
        float c = (r1 < 511) ? tmp12[r1 * 511 + c0] : 0.f;
        float d = (r1 < 511 && c1 < 511) ? tmp12[r1 * 511 + c1] : 0.f;
        float lo0 = (a + b) * INV, hi0 = (a - b) * INV;
        float lo1 = (c + d) * INV, hi1 = (c - d) * INV;
        float cH = (lo0 - lo1) * INV;
        float cV = (hi0 + hi1) * INV;
        float cD = (hi0 - hi1) * INV;
#pragma unroll
        for (int o = 0; o < 4; ++o)
            v[o] = fmaxf(wh[o * 3 + 0] * cH + wh[o * 3 + 1] * cV + wh[o * 3 + 2] * cD + bh[o], 0.f);
    }
    int orow = (2 * h) * 516 + 2 * w;
    hf[orow]       = v[0];
    hf[orow + 1]   = v[1];
    hf[orow + 516] = v[2];
    hf[orow + 517] = v[3];
}

// ---------------- K3: 5x5 separable gaussian blur, reflect pad --------------
__global__ __launch_bounds__(256) void k_blur(const float* __restrict__ hf,
                                              float* __restrict__ hfb,
                                              float g0, float g1, float g2)
{
    int idx = blockIdx.x * 256 + threadIdx.x;
    if (idx >= 516 * 516) return;
    int y = idx / 516, x = idx - y * 516;
    float g[5] = {g0, g1, g2, g1, g0};
    int ry[5], rx[5];
#pragma unroll
    for (int i = 0; i < 5; ++i) {
        int yy = y + i - 2; yy = yy < 0 ? -yy : (yy > 515 ? 1030 - yy : yy);
        int xx = x + i - 2; xx = xx < 0 ? -xx : (xx > 515 ? 1030 - xx : xx);
        ry[i] = yy * 516; rx[i] = xx;
    }
    float s = 0.f;
#pragma unroll
    for (int i = 0; i < 5; ++i) {
        float rs = 0.f;
#pragma unroll
        for (int j = 0; j < 5; ++j) rs = fmaf(g[j], hf[ry[i] + rx[j]], rs);
        s = fmaf(g[i], rs, s);
    }
    hfb[idx] = s;
}

// ---------------- K4: global mean/max reduction -> sigmoid gate -------------
__global__ __launch_bounds__(256) void k_red1(const float* __restrict__ hfb,
                                              float* __restrict__ psum,
                                              float* __restrict__ pmax)
{
    __shared__ float ss[256], sm[256];
    int t = threadIdx.x;
    int gid = blockIdx.x * 256 + t;
    float s = 0.f, m = -3.4e38f;
    for (int i = gid; i < 516 * 516; i += 65536) { float v = hfb[i]; s += v; m = fmaxf(m, v); }
    ss[t] = s; sm[t] = m;
    __syncthreads();
    for (int off = 128; off > 0; off >>= 1) {
        if (t < off) { ss[t] += ss[t + off]; sm[t] = fmaxf(sm[t], sm[t + off]); }
        __syncthreads();
    }
    if (t == 0) { psum[blockIdx.x] = ss[0]; pmax[blockIdx.x] = sm[0]; }
}

__global__ __launch_bounds__(256) void k_red2(const float* __restrict__ psum,
                                              const float* __restrict__ pmax,
                                              const float* __restrict__ caw1,
                                              const float* __restrict__ caw2,
                                              float* __restrict__ scale)
{
    __shared__ float ss[256], sm[256];
    int t = threadIdx.x;
    ss[t] = psum[t]; sm[t] = pmax[t];
    __syncthreads();
    for (int off = 128; off > 0; off >>= 1) {
        if (t < off) { ss[t] += ss[t + off]; sm[t] = fmaxf(sm[t], sm[t + off]); }
        __syncthreads();
    }
    if (t == 0) {
        float avg = ss[0] / 266256.f;
        float mx = sm[0];
        float a = caw1[0], b = caw2[0];
        float z = b * fmaxf(a * avg, 0.f) + b * fmaxf(a * mx, 0.f);
        scale[0] = 1.f / (1.f + expf(-z));
    }
}

// ---------------- K5: 6x6 valid conv (scale folded) + bias + relu + residual
__global__ __launch_bounds__(256) void k_cat(const float* __restrict__ hfb,
                                             const float* __restrict__ tmp12,
                                             const float* __restrict__ w_cat,
                                             const float* __restrict__ b_cat,
                                             const float* __restrict__ scale,
                                             float* __restrict__ f12)
{
    int p = blockIdx.x * 256 + threadIdx.x;
    if (p >= NP) return;
    int y = p / 511, x = p - y * 511;
    float sc = scale[0];
    float s = 0.f;
#pragma unroll
    for (int ky = 0; ky < 6; ++ky) {
        const float* row = hfb + (y + ky) * 516 + x;
#pragma unroll
        for (int kx = 0; kx < 6; ++kx) s = fmaf(row[kx], w_cat[ky * 6 + kx], s);
    }
    f12[p] = tmp12[p] + fmaxf(sc * s + b_cat[0], 0.f);
}

// ---------------- K6: 3x3 conv 1->32, pad 1, relu -> bf16 4-plane h2 --------
__global__ __launch_bounds__(256) void k_c9a(const float* __restrict__ f12,
                                             const float* __restrict__ wTa,
                                             const float* __restrict__ bias,
                                             unsigned short* __restrict__ h2)
{
    int p = blockIdx.x * 256 + threadIdx.x;
    if (p >= NP) return;
    int y = p / 511, x = p - y * 511;
    float hv[9];
#pragma unroll
    for (int ky = 0; ky < 3; ++ky)
#pragma unroll
        for (int kx = 0; kx < 3; ++kx) {
            int yy = y + ky - 1, xx = x + kx - 1;
            hv[ky * 3 + kx] = (yy >= 0 && yy < 511 && xx >= 0 && xx < 511) ? f12[yy * 511 + xx] : 0.f;
        }
    float acc[32];
#pragma unroll
    for (int o = 0; o < 32; ++o) acc[o] = bias[o];
#pragma unroll
    for (int k = 0; k < 9; ++k) {
        float v = hv[k];
        const float* wp = wTa + k * 32;   // uniform -> s_load
#pragma unroll
        for (int o = 0; o < 32; ++o) acc[o] = fmaf(v, wp[o], acc[o]);
    }
    unsigned short o16[32];
#pragma unroll
    for (int o = 0; o < 32; ++o) o16[o] = f2bf(fmaxf(acc[o], 0.f));
    size_t px = (size_t)(y + 1) * WPX + (x + 1);
#pragma unroll
    for (int i = 0; i < 4; ++i)   // lane-contiguous 1KB stores per plane
        *reinterpret_cast<short8*>(h2 + (size_t)i * PSTR + px * 8) =
            reinterpret_cast<const short8*>(o16)[i];
}

// ---------------- K7: 3x3 conv 32->64 via MFMA implicit GEMM ----------------
__global__ __launch_bounds__(256, 2) void k_c9b(const unsigned short* __restrict__ h2,
                                                const unsigned short* __restrict__ wb2,
                                                const float* __restrict__ bias,
                                                float* __restrict__ out)
{
    // bijective XCD swizzle: nwg=1022, q=127, r=6 -> each XCD owns ~64 rows
    int bid = blockIdx.x;
    int xcd = bid & 7, jj = bid >> 3;
    const int q = 127, r = 6;
    int wg = (xcd < r ? xcd * (q + 1) : r * (q + 1) + (xcd - r) * q) + jj;

    int wave = threadIdx.x >> 6, lane = threadIdx.x & 63;
    int y  = wg >> 1;                 // 0..510
    int xh = wg & 1;
    int xb = xh * 256 + wave * 64;
    int lpx = lane & 15, kg = lane >> 4;

    f32x4 acc[4][4];
#pragma unroll
    for (int m = 0; m < 4; ++m)
#pragma unroll
        for (int n = 0; n < 4; ++n) acc[m][n] = (f32x4){0.f, 0.f, 0.f, 0.f};

    const size_t pbase = (size_t)kg * PSTR;
    const int base_px = (y + 1) * WPX + (xb + 1) + lpx;

#pragma unroll
    for (int kt = 0; kt < 9; ++kt) {
        const int dy = kt / 3 - 1, dx = kt % 3 - 1;
        const int tpx = dy * WPX + dx;

        short8 a[4], b[4];
        const short8* wp = reinterpret_cast<const short8*>(wb2 + kt * 2048 + kg * 8);
#pragma unroll
        for (int m = 0; m < 4; ++m) a[m] = wp[(m * 16 + lpx) * 4];
#pragma unroll
        for (int n = 0; n < 4; ++n)
            b[n] = *reinterpret_cast<const short8*>(h2 + pbase + (size_t)(base_px + tpx + n * 16) * 8);
#pragma unroll
        for (int m = 0; m < 4; ++m)
#pragma unroll
            for (int n = 0; n < 4; ++n)
                acc[m][n] = __builtin_amdgcn_mfma_f32_16x16x32_bf16(a[m], b[n], acc[m][n], 0, 0, 0);
    }

    const int ybase = y * 511;
#pragma unroll
    for (int m = 0; m < 4; ++m) {
#pragma unroll
        for (int rr = 0; rr < 4; ++rr) {
            int o = m * 16 + kg * 4 + rr;
            float bo = bias[o];
#pragma unroll
            for (int n = 0; n < 4; ++n) {
                int px = xb + n * 16 + lpx;
                if (px < 511)
                    out[(size_t)o * NP + ybase + px] = fmaxf(acc[m][n][rr] + bo, 0.f);
            }
        }
    }
}

// ---------------------------------------------------------------------------
extern "C" void kernel_launch(void* const* d_in, const int* in_sizes, int n_in,
                              void* d_out, int out_size, void* d_ws, size_t ws_size,
                              hipStream_t stream)
{
    (void)in_sizes; (void)n_in; (void)out_size; (void)ws_size;

    const float* x     = (const float*)d_in[0];
    const float* w_x1  = (const float*)d_in[1];
    const float* b_x1  = (const float*)d_in[2];
    const float* w_x2  = (const float*)d_in[3];
    const float* b_x2  = (const float*)d_in[4];
    const float* w_x3  = (const float*)d_in[5];
    const float* b_x3  = (const float*)d_in[6];
    const float* w_hi  = (const float*)d_in[7];
    const float* b_hi  = (const float*)d_in[8];
    const float* ca1w1 = (const float*)d_in[11];
    const float* ca1w2 = (const float*)d_in[12];
    const float* w_cat = (const float*)d_in[15];
    const float* b_cat = (const float*)d_in[16];
    const float* w_c9a = (const float*)d_in[17];
    const float* b_c9a = (const float*)d_in[18];
    const float* w_c9b = (const float*)d_in[19];
    const float* b_c9b = (const float*)d_in[20];

    float* ws    = (float*)d_ws;
    float* tmp12 = ws + 0;                       // 261184
    float* hf    = ws + 261184;                  // 266304
    float* hfb   = ws + 527488;                  // 266304
    float* f12   = ws + 793792;                  // 261184
    float* psum  = ws + 1054976;                 // 256
    float* pmax  = ws + 1055232;                 // 256
    float* scale = ws + 1055488;                 // 64
    float* wTa   = ws + 1055552;                 // 320
    float* wT1   = ws + 1055872;                 // 3264 -> 3328
    unsigned short* wb2 = (unsigned short*)(ws + 1059200);   // 18432 ushorts
    unsigned short* h2  = (unsigned short*)(ws + 1068416);   // 4*PSTR ushorts (~17.1 MB)

    float* out = (float*)d_out;

    double kk[5], ssum = 0.0;
    for (int i = 0; i < 5; ++i) { double r = i - 2.0; kk[i] = exp(-r * r / 0.5); ssum += kk[i]; }
    float g0 = (float)(kk[0] / ssum), g1 = (float)(kk[1] / ssum), g2 = (float)(kk[2] / ssum);

    k_prep<<<72, 256, 0, stream>>>(w_c9a, w_c9b, w_x1, wTa, wb2, wT1, h2);
    k_conv123<<<1021, 256, 0, stream>>>(x, wT1, b_x1, w_x2, b_x2, w_x3, b_x3, tmp12);
    k_dwt_hi<<<261, 256, 0, stream>>>(tmp12, w_hi, b_hi, hf);
    k_blur<<<1041, 256, 0, stream>>>(hf, hfb, g0, g1, g2);
    k_red1<<<256, 256, 0, stream>>>(hfb, psum, pmax);
    k_red2<<<1, 256, 0, stream>>>(psum, pmax, ca1w1, ca1w2, scale);
    k_cat<<<1021, 256, 0, stream>>>(hfb, tmp12, w_cat, b_cat, scale, f12);
    k_c9a<<<1021, 256, 0, stream>>>(f12, wTa, b_c9a, h2);
    k_c9b<<<1022, 256, 0, stream>>>(h2, wb2, b_c9b, out);
}

// Round 4
// 122.217 us; speedup vs baseline: 1.1414x; 1.1414x over previous
//
#include <hip/hip_runtime.h>
#include <math.h>

#define NP   261121   // 511*511
#define HALF 130561   // ceil(NP/2)
#define WPX  520      // padded pixel row stride (rows 0..513, interior cols 1..511)
#define ROWN 4160     // WPX*8 ushorts per plane-row
#define PSTR 2138240  // 514*ROWN ushorts per channel-group plane

typedef __attribute__((ext_vector_type(8))) short short8;
typedef __attribute__((ext_vector_type(4))) float f32x4;

static __device__ __forceinline__ unsigned short f2bf(float f) {
    unsigned int u = __builtin_bit_cast(unsigned int, f);
    u += 0x7FFFu + ((u >> 16) & 1u);   // round-to-nearest-even
    return (unsigned short)(u >> 16);
}

// ---------------- K0: weight prep + h2 pad-ring zero ------------------------
__global__ __launch_bounds__(256) void k_prep(const float* __restrict__ w_c9a,
                                              const float* __restrict__ w_c9b,
                                              const float* __restrict__ w_x1,
                                              float* __restrict__ wTa,
                                              unsigned short* __restrict__ wb2,
                                              float* __restrict__ wT1,
                                              unsigned short* __restrict__ h2)
{
    int t = blockIdx.x * 256 + threadIdx.x;
    if (t < 288)  wTa[t] = w_c9a[(t & 31) * 9 + (t >> 5)];
    if (t < 3264) wT1[t] = w_x1[(t & 15) * 204 + (t >> 4)];
    if (t < 18432) {
        int o = t / 288, ck = t - o * 288;
        int c = ck / 9, k = ck - c * 9;
        wb2[k * 2048 + o * 32 + c] = f2bf(w_c9b[t]);
    }
    short8 z8 = {0, 0, 0, 0, 0, 0, 0, 0};
    if (t < 4160) {                                 // rows 0 & 512, all planes
        int pl = t / 1040;
        int rr = t - pl * 1040;
        int row = rr >= 520 ? 512 : 0;
        int ch  = rr >= 520 ? rr - 520 : rr;
        *reinterpret_cast<short8*>(h2 + (size_t)pl * PSTR + (size_t)row * ROWN + ch * 8) = z8;
    }
    int z = t - 4160;
    if (z >= 0 && z < 6132) {                       // rows 1..511, cols {0,512,513}
        int row = z / 12 + 1;
        int j = z - (row - 1) * 12;
        int pl = j / 3, cidx = j - pl * 3;
        int col = (cidx == 0) ? 0 : (cidx == 1 ? 512 : 513);
        *reinterpret_cast<short8*>(h2 + (size_t)pl * PSTR + (size_t)row * ROWN + col * 8) = z8;
    }
}

// ---------------- K1: fused 1x1 convs 204->16->8->1, 2 px/thread ------------
__global__ __launch_bounds__(512) void k_conv123(const float* __restrict__ x,
                                                 const float* __restrict__ wT1,
                                                 const float* __restrict__ b1,
                                                 const float* __restrict__ w2,
                                                 const float* __restrict__ b2,
                                                 const float* __restrict__ w3,
                                                 const float* __restrict__ b3,
                                                 float* __restrict__ tmp12)
{
    __shared__ float sw[3264];
    int t = threadIdx.x;
    for (int i = t; i < 3264; i += 512) sw[i] = wT1[i];
    __syncthreads();

    int g = blockIdx.x * 512 + t;
    if (g >= HALF) return;
    int p0 = g, p1 = g + HALF;
    bool has1 = p1 < NP;
    int p1c = has1 ? p1 : p0;

    float acc0[16], acc1[16];
#pragma unroll
    for (int o = 0; o < 16; ++o) { acc0[o] = 0.f; acc1[o] = 0.f; }

#pragma unroll 4
    for (int c = 0; c < 204; ++c) {
        float xv0 = x[c * NP + p0];
        float xv1 = x[c * NP + p1c];
        const float4* wv = reinterpret_cast<const float4*>(sw + c * 16);
        float wl[16];
        *reinterpret_cast<float4*>(&wl[0])  = wv[0];
        *reinterpret_cast<float4*>(&wl[4])  = wv[1];
        *reinterpret_cast<float4*>(&wl[8])  = wv[2];
        *reinterpret_cast<float4*>(&wl[12]) = wv[3];
#pragma unroll
        for (int o = 0; o < 16; ++o) {
            acc0[o] = fmaf(xv0, wl[o], acc0[o]);
            acc1[o] = fmaf(xv1, wl[o], acc1[o]);
        }
    }

    float r0 = b3[0], r1 = b3[0];
    {
        float f10[16], f11[16];
#pragma unroll
        for (int o = 0; o < 16; ++o) {
            float bo = b1[o];
            f10[o] = fmaxf(acc0[o] + bo, 0.f);
            f11[o] = fmaxf(acc1[o] + bo, 0.f);
        }
#pragma unroll
        for (int j = 0; j < 8; ++j) {
            float s0 = b2[j], s1 = b2[j];
#pragma unroll
            for (int o = 0; o < 16; ++o) {
                float w = w2[j * 16 + o];
                s0 = fmaf(f10[o], w, s0);
                s1 = fmaf(f11[o], w, s1);
            }
            float wj = w3[j];
            r0 = fmaf(fmaxf(s0, 0.f), wj, r0);
            r1 = fmaf(fmaxf(s1, 0.f), wj, r1);
        }
    }
    tmp12[p0] = fmaxf(r0, 0.f);
    if (has1) tmp12[p1] = fmaxf(r1, 0.f);
}

// ------------- K2: Haar DWT (zero-pad) + 1x1 conv(pad=1) + pixel_shuffle ----
__global__ __launch_bounds__(256) void k_dwt_hi(const float* __restrict__ tmp12,
                                                const float* __restrict__ w_hi,
                                                const float* __restrict__ b_hi,
                                                float* __restrict__ hf)
{
    const float INV = 0.70710678118654752440f;
    int idx = blockIdx.x * 256 + threadIdx.x;
    if (idx >= 258 * 258) return;
    int h = idx / 258, w = idx - h * 258;

    float wh[12], bh[4];
#pragma unroll
    for (int i = 0; i < 12; ++i) wh[i] = w_hi[i];
#pragma unroll
    for (int o = 0; o < 4; ++o) bh[o] = b_hi[o];

    float v[4];
    if (h == 0 || h == 257 || w == 0 || w == 257) {
#pragma unroll
        for (int o = 0; o < 4; ++o) v[o] = fmaxf(bh[o], 0.f);
    } else {
        int hh = h - 1, ww = w - 1;
        int r0 = 2 * hh, r1 = 2 * hh + 1, c0 = 2 * ww, c1 = 2 * ww + 1;
        float a = tmp12[r0 * 511 + c0];
        float b = (c1 < 511) ? tmp12[r0 * 511 + c1] : 0.f;
        float c = (r1 < 511) ? tmp12[r1 * 511 + c0] : 0.f;
        float d = (r1 < 511 && c1 < 511) ? tmp12[r1 * 511 + c1] : 0.f;
        float lo0 = (a + b) * INV, hi0 = (a - b) * INV;
        float lo1 = (c + d) * INV, hi1 = (c - d) * INV;
        float cH = (lo0 - lo1) * INV;
        float cV = (hi0 + hi1) * INV;
        float cD = (hi0 - hi1) * INV;
#pragma unroll
        for (int o = 0; o < 4; ++o)
            v[o] = fmaxf(wh[o * 3 + 0] * cH + wh[o * 3 + 1] * cV + wh[o * 3 + 2] * cD + bh[o], 0.f);
    }
    int orow = (2 * h) * 516 + 2 * w;
    hf[orow]       = v[0];
    hf[orow + 1]   = v[1];
    hf[orow + 516] = v[2];
    hf[orow + 517] = v[3];
}

// ---------------- K3: 5x5 separable gaussian blur, reflect pad --------------
__global__ __launch_bounds__(256) void k_blur(const float* __restrict__ hf,
                                              float* __restrict__ hfb,
                                              float g0, float g1, float g2)
{
    int idx = blockIdx.x * 256 + threadIdx.x;
    if (idx >= 516 * 516) return;
    int y = idx / 516, x = idx - y * 516;
    float g[5] = {g0, g1, g2, g1, g0};
    int ry[5], rx[5];
#pragma unroll
    for (int i = 0; i < 5; ++i) {
        int yy = y + i - 2; yy = yy < 0 ? -yy : (yy > 515 ? 1030 - yy : yy);
        int xx = x + i - 2; xx = xx < 0 ? -xx : (xx > 515 ? 1030 - xx : xx);
        ry[i] = yy * 516; rx[i] = xx;
    }
    float s = 0.f;
#pragma unroll
    for (int i = 0; i < 5; ++i) {
        float rs = 0.f;
#pragma unroll
        for (int j = 0; j < 5; ++j) rs = fmaf(g[j], hf[ry[i] + rx[j]], rs);
        s = fmaf(g[i], rs, s);
    }
    hfb[idx] = s;
}

// ---------------- K4: global mean/max reduction -> sigmoid gate -------------
__global__ __launch_bounds__(256) void k_red1(const float* __restrict__ hfb,
                                              float* __restrict__ psum,
                                              float* __restrict__ pmax)
{
    __shared__ float ss[256], sm[256];
    int t = threadIdx.x;
    int gid = blockIdx.x * 256 + t;
    float s = 0.f, m = -3.4e38f;
    for (int i = gid; i < 516 * 516; i += 65536) { float v = hfb[i]; s += v; m = fmaxf(m, v); }
    ss[t] = s; sm[t] = m;
    __syncthreads();
    for (int off = 128; off > 0; off >>= 1) {
        if (t < off) { ss[t] += ss[t + off]; sm[t] = fmaxf(sm[t], sm[t + off]); }
        __syncthreads();
    }
    if (t == 0) { psum[blockIdx.x] = ss[0]; pmax[blockIdx.x] = sm[0]; }
}

__global__ __launch_bounds__(256) void k_red2(const float* __restrict__ psum,
                                              const float* __restrict__ pmax,
                                              const float* __restrict__ caw1,
                                              const float* __restrict__ caw2,
                                              float* __restrict__ scale)
{
    __shared__ float ss[256], sm[256];
    int t = threadIdx.x;
    ss[t] = psum[t]; sm[t] = pmax[t];
    __syncthreads();
    for (int off = 128; off > 0; off >>= 1) {
        if (t < off) { ss[t] += ss[t + off]; sm[t] = fmaxf(sm[t], sm[t + off]); }
        __syncthreads();
    }
    if (t == 0) {
        float avg = ss[0] / 266256.f;
        float mx = sm[0];
        float a = caw1[0], b = caw2[0];
        float z = b * fmaxf(a * avg, 0.f) + b * fmaxf(a * mx, 0.f);
        scale[0] = 1.f / (1.f + expf(-z));
    }
}

// ---------------- K5: 6x6 valid conv (scale folded) + bias + relu + residual
__global__ __launch_bounds__(256) void k_cat(const float* __restrict__ hfb,
                                             const float* __restrict__ tmp12,
                                             const float* __restrict__ w_cat,
                                             const float* __restrict__ b_cat,
                                             const float* __restrict__ scale,
                                             float* __restrict__ f12)
{
    int p = blockIdx.x * 256 + threadIdx.x;
    if (p >= NP) return;
    int y = p / 511, x = p - y * 511;
    float sc = scale[0];
    float s = 0.f;
#pragma unroll
    for (int ky = 0; ky < 6; ++ky) {
        const float* row = hfb + (y + ky) * 516 + x;
#pragma unroll
        for (int kx = 0; kx < 6; ++kx) s = fmaf(row[kx], w_cat[ky * 6 + kx], s);
    }
    f12[p] = tmp12[p] + fmaxf(sc * s + b_cat[0], 0.f);
}

// ---------------- K6: 3x3 conv 1->32, pad 1, relu -> bf16 4-plane h2 --------
__global__ __launch_bounds__(256) void k_c9a(const float* __restrict__ f12,
                                             const float* __restrict__ wTa,
                                             const float* __restrict__ bias,
                                             unsigned short* __restrict__ h2)
{
    int p = blockIdx.x * 256 + threadIdx.x;
    if (p >= NP) return;
    int y = p / 511, x = p - y * 511;
    float hv[9];
#pragma unroll
    for (int ky = 0; ky < 3; ++ky)
#pragma unroll
        for (int kx = 0; kx < 3; ++kx) {
            int yy = y + ky - 1, xx = x + kx - 1;
            hv[ky * 3 + kx] = (yy >= 0 && yy < 511 && xx >= 0 && xx < 511) ? f12[yy * 511 + xx] : 0.f;
        }
    float acc[32];
#pragma unroll
    for (int o = 0; o < 32; ++o) acc[o] = bias[o];
#pragma unroll
    for (int k = 0; k < 9; ++k) {
        float v = hv[k];
        const float* wp = wTa + k * 32;
#pragma unroll
        for (int o = 0; o < 32; ++o) acc[o] = fmaf(v, wp[o], acc[o]);
    }
    unsigned short o16[32];
#pragma unroll
    for (int o = 0; o < 32; ++o) o16[o] = f2bf(fmaxf(acc[o], 0.f));
    size_t px = (size_t)(y + 1) * WPX + (x + 1);
#pragma unroll
    for (int i = 0; i < 4; ++i)
        *reinterpret_cast<short8*>(h2 + (size_t)i * PSTR + px * 8) =
            reinterpret_cast<const short8*>(o16)[i];
}

// ---------------- K7: 3x3 conv 32->64 via MFMA implicit GEMM ----------------
__global__ __launch_bounds__(256, 2) void k_c9b(const unsigned short* __restrict__ h2,
                                                const unsigned short* __restrict__ wb2,
                                                const float* __restrict__ bias,
                                                float* __restrict__ out)
{
    int bid = blockIdx.x;
    int xcd = bid & 7, jj = bid >> 3;
    const int q = 127, r = 6;
    int wg = (xcd < r ? xcd * (q + 1) : r * (q + 1) + (xcd - r) * q) + jj;

    int wave = threadIdx.x >> 6, lane = threadIdx.x & 63;
    int y  = wg >> 1;
    int xh = wg & 1;
    int xb = xh * 256 + wave * 64;
    int lpx = lane & 15, kg = lane >> 4;

    f32x4 acc[4][4];
#pragma unroll
    for (int m = 0; m < 4; ++m)
#pragma unroll
        for (int n = 0; n < 4; ++n) acc[m][n] = (f32x4){0.f, 0.f, 0.f, 0.f};

    const size_t pbase = (size_t)kg * PSTR;
    const int base_px = (y + 1) * WPX + (xb + 1) + lpx;

#pragma unroll
    for (int kt = 0; kt < 9; ++kt) {
        const int dy = kt / 3 - 1, dx = kt % 3 - 1;
        const int tpx = dy * WPX + dx;

        short8 a[4], b[4];
        const short8* wp = reinterpret_cast<const short8*>(wb2 + kt * 2048 + kg * 8);
#pragma unroll
        for (int m = 0; m < 4; ++m) a[m] = wp[(m * 16 + lpx) * 4];
#pragma unroll
        for (int n = 0; n < 4; ++n)
            b[n] = *reinterpret_cast<const short8*>(h2 + pbase + (size_t)(base_px + tpx + n * 16) * 8);
#pragma unroll
        for (int m = 0; m < 4; ++m)
#pragma unroll
            for (int n = 0; n < 4; ++n)
                acc[m][n] = __builtin_amdgcn_mfma_f32_16x16x32_bf16(a[m], b[n], acc[m][n], 0, 0, 0);
    }

    const int ybase = y * 511;
#pragma unroll
    for (int m = 0; m < 4; ++m) {
#pragma unroll
        for (int rr = 0; rr < 4; ++rr) {
            int o = m * 16 + kg * 4 + rr;
            float bo = bias[o];
#pragma unroll
            for (int n = 0; n < 4; ++n) {
                int px = xb + n * 16 + lpx;
                if (px < 511)
                    out[(size_t)o * NP + ybase + px] = fmaxf(acc[m][n][rr] + bo, 0.f);
            }
        }
    }
}

// ---------------------------------------------------------------------------
extern "C" void kernel_launch(void* const* d_in, const int* in_sizes, int n_in,
                              void* d_out, int out_size, void* d_ws, size_t ws_size,
                              hipStream_t stream)
{
    (void)in_sizes; (void)n_in; (void)out_size; (void)ws_size;

    const float* x     = (const float*)d_in[0];
    const float* w_x1  = (const float*)d_in[1];
    const float* b_x1  = (const float*)d_in[2];
    const float* w_x2  = (const float*)d_in[3];
    const float* b_x2  = (const float*)d_in[4];
    const float* w_x3  = (const float*)d_in[5];
    const float* b_x3  = (const float*)d_in[6];
    const float* w_hi  = (const float*)d_in[7];
    const float* b_hi  = (const float*)d_in[8];
    const float* ca1w1 = (const float*)d_in[11];
    const float* ca1w2 = (const float*)d_in[12];
    const float* w_cat = (const float*)d_in[15];
    const float* b_cat = (const float*)d_in[16];
    const float* w_c9a = (const float*)d_in[17];
    const float* b_c9a = (const float*)d_in[18];
    const float* w_c9b = (const float*)d_in[19];
    const float* b_c9b = (const float*)d_in[20];

    float* ws    = (float*)d_ws;
    float* tmp12 = ws + 0;                       // 261184
    float* hf    = ws + 261184;                  // 266304
    float* hfb   = ws + 527488;                  // 266304
    float* f12   = ws + 793792;                  // 261184
    float* psum  = ws + 1054976;                 // 256
    float* pmax  = ws + 1055232;                 // 256
    float* scale = ws + 1055488;                 // 64
    float* wTa   = ws + 1055552;                 // 320
    float* wT1   = ws + 1055872;                 // 3264 -> 3328
    unsigned short* wb2 = (unsigned short*)(ws + 1059200);   // 18432 ushorts
    unsigned short* h2  = (unsigned short*)(ws + 1068416);   // 4*PSTR ushorts

    float* out = (float*)d_out;

    double kk[5], ssum = 0.0;
    for (int i = 0; i < 5; ++i) { double r = i - 2.0; kk[i] = exp(-r * r / 0.5); ssum += kk[i]; }
    float g0 = (float)(kk[0] / ssum), g1 = (float)(kk[1] / ssum), g2 = (float)(kk[2] / ssum);

    k_prep<<<72, 256, 0, stream>>>(w_c9a, w_c9b, w_x1, wTa, wb2, wT1, h2);
    k_conv123<<<256, 512, 0, stream>>>(x, wT1, b_x1, w_x2, b_x2, w_x3, b_x3, tmp12);
    k_dwt_hi<<<261, 256, 0, stream>>>(tmp12, w_hi, b_hi, hf);
    k_blur<<<1041, 256, 0, stream>>>(hf, hfb, g0, g1, g2);
    k_red1<<<256, 256, 0, stream>>>(hfb, psum, pmax);
    k_red2<<<1, 256, 0, stream>>>(psum, pmax, ca1w1, ca1w2, scale);
    k_cat<<<1021, 256, 0, stream>>>(hfb, tmp12, w_cat, b_cat, scale, f12);
    k_c9a<<<1021, 256, 0, stream>>>(f12, wTa, b_c9a, h2);
    k_c9b<<<1022, 256, 0, stream>>>(h2, wb2, b_c9b, out);
}

// Round 5
// 115.055 us; speedup vs baseline: 1.2125x; 1.0623x over previous
//
#include <hip/hip_runtime.h>
#include <math.h>

#define NP    261121   // 511*511
#define HALF  130561   // ceil(NP/2)
#define WPX   520      // padded pixel row stride (rows 0..513, interior cols 1..511)
#define ROWN  4160     // WPX*8 ushorts per plane-row
#define PSTR  2138240  // 514*ROWN ushorts per channel-group plane
#define NBLUR 1041     // blur grid blocks (= partial count)

typedef __attribute__((ext_vector_type(8))) short short8;
typedef __attribute__((ext_vector_type(4))) float f32x4;

static __device__ __forceinline__ unsigned short f2bf(float f) {
    unsigned int u = __builtin_bit_cast(unsigned int, f);
    u += 0x7FFFu + ((u >> 16) & 1u);   // round-to-nearest-even
    return (unsigned short)(u >> 16);
}

// ---------------- K0: weight prep + h2 pad-ring zero ------------------------
__global__ __launch_bounds__(256) void k_prep(const float* __restrict__ w_c9a,
                                              const float* __restrict__ w_c9b,
                                              const float* __restrict__ w_x1,
                                              float* __restrict__ wTa,
                                              unsigned short* __restrict__ wb2,
                                              float* __restrict__ wT1,
                                              unsigned short* __restrict__ h2)
{
    int t = blockIdx.x * 256 + threadIdx.x;
    if (t < 288)  wTa[t] = w_c9a[(t & 31) * 9 + (t >> 5)];
    if (t < 3264) wT1[t] = w_x1[(t & 15) * 204 + (t >> 4)];
    if (t < 18432) {
        int o = t / 288, ck = t - o * 288;
        int c = ck / 9, k = ck - c * 9;
        wb2[k * 2048 + o * 32 + c] = f2bf(w_c9b[t]);
    }
    short8 z8 = {0, 0, 0, 0, 0, 0, 0, 0};
    if (t < 4160) {                                 // rows 0 & 512, all planes
        int pl = t / 1040;
        int rr = t - pl * 1040;
        int row = rr >= 520 ? 512 : 0;
        int ch  = rr >= 520 ? rr - 520 : rr;
        *reinterpret_cast<short8*>(h2 + (size_t)pl * PSTR + (size_t)row * ROWN + ch * 8) = z8;
    }
    int z = t - 4160;
    if (z >= 0 && z < 6132) {                       // rows 1..511, cols {0,512,513}
        int row = z / 12 + 1;
        int j = z - (row - 1) * 12;
        int pl = j / 3, cidx = j - pl * 3;
        int col = (cidx == 0) ? 0 : (cidx == 1 ? 512 : 513);
        *reinterpret_cast<short8*>(h2 + (size_t)pl * PSTR + (size_t)row * ROWN + col * 8) = z8;
    }
}

// ---------------- K1: fused 1x1 convs 204->16->8->1, 2 px/thread ------------
__global__ __launch_bounds__(512) void k_conv123(const float* __restrict__ x,
                                                 const float* __restrict__ wT1,
                                                 const float* __restrict__ b1,
                                                 const float* __restrict__ w2,
                                                 const float* __restrict__ b2,
                                                 const float* __restrict__ w3,
                                                 const float* __restrict__ b3,
                                                 float* __restrict__ tmp12)
{
    __shared__ float sw[3264];
    int t = threadIdx.x;
    for (int i = t; i < 3264; i += 512) sw[i] = wT1[i];
    __syncthreads();

    int g = blockIdx.x * 512 + t;
    if (g >= HALF) return;
    int p0 = g, p1 = g + HALF;
    bool has1 = p1 < NP;
    int p1c = has1 ? p1 : p0;

    float acc0[16], acc1[16];
#pragma unroll
    for (int o = 0; o < 16; ++o) { acc0[o] = 0.f; acc1[o] = 0.f; }

#pragma unroll 4
    for (int c = 0; c < 204; ++c) {
        float xv0 = x[c * NP + p0];
        float xv1 = x[c * NP + p1c];
        const float4* wv = reinterpret_cast<const float4*>(sw + c * 16);
        float wl[16];
        *reinterpret_cast<float4*>(&wl[0])  = wv[0];
        *reinterpret_cast<float4*>(&wl[4])  = wv[1];
        *reinterpret_cast<float4*>(&wl[8])  = wv[2];
        *reinterpret_cast<float4*>(&wl[12]) = wv[3];
#pragma unroll
        for (int o = 0; o < 16; ++o) {
            acc0[o] = fmaf(xv0, wl[o], acc0[o]);
            acc1[o] = fmaf(xv1, wl[o], acc1[o]);
        }
    }

    float r0 = b3[0], r1 = b3[0];
    {
        float f10[16], f11[16];
#pragma unroll
        for (int o = 0; o < 16; ++o) {
            float bo = b1[o];
            f10[o] = fmaxf(acc0[o] + bo, 0.f);
            f11[o] = fmaxf(acc1[o] + bo, 0.f);
        }
#pragma unroll
        for (int j = 0; j < 8; ++j) {
            float s0 = b2[j], s1 = b2[j];
#pragma unroll
            for (int o = 0; o < 16; ++o) {
                float w = w2[j * 16 + o];
                s0 = fmaf(f10[o], w, s0);
                s1 = fmaf(f11[o], w, s1);
            }
            float wj = w3[j];
            r0 = fmaf(fmaxf(s0, 0.f), wj, r0);
            r1 = fmaf(fmaxf(s1, 0.f), wj, r1);
        }
    }
    tmp12[p0] = fmaxf(r0, 0.f);
    if (has1) tmp12[p1] = fmaxf(r1, 0.f);
}

// ------------- K2: Haar DWT (zero-pad) + 1x1 conv(pad=1) + pixel_shuffle ----
__global__ __launch_bounds__(256) void k_dwt_hi(const float* __restrict__ tmp12,
                                                const float* __restrict__ w_hi,
                                                const float* __restrict__ b_hi,
                                                float* __restrict__ hf)
{
    const float INV = 0.70710678118654752440f;
    int idx = blockIdx.x * 256 + threadIdx.x;
    if (idx >= 258 * 258) return;
    int h = idx / 258, w = idx - h * 258;

    float wh[12], bh[4];
#pragma unroll
    for (int i = 0; i < 12; ++i) wh[i] = w_hi[i];
#pragma unroll
    for (int o = 0; o < 4; ++o) bh[o] = b_hi[o];

    float v[4];
    if (h == 0 || h == 257 || w == 0 || w == 257) {
#pragma unroll
        for (int o = 0; o < 4; ++o) v[o] = fmaxf(bh[o], 0.f);
    } else {
        int hh = h - 1, ww = w - 1;
        int r0 = 2 * hh, r1 = 2 * hh + 1, c0 = 2 * ww, c1 = 2 * ww + 1;
        float a = tmp12[r0 * 511 + c0];
        float b = (c1 < 511) ? tmp12[r0 * 511 + c1] : 0.f;
        float c = (r1 < 511) ? tmp12[r1 * 511 + c0] : 0.f;
        float d = (r1 < 511 && c1 < 511) ? tmp12[r1 * 511 + c1] : 0.f;
        float lo0 = (a + b) * INV, hi0 = (a - b) * INV;
        float lo1 = (c + d) * INV, hi1 = (c - d) * INV;
        float cH = (lo0 - lo1) * INV;
        float cV = (hi0 + hi1) * INV;
        float cD = (hi0 - hi1) * INV;
#pragma unroll
        for (int o = 0; o < 4; ++o)
            v[o] = fmaxf(wh[o * 3 + 0] * cH + wh[o * 3 + 1] * cV + wh[o * 3 + 2] * cD + bh[o], 0.f);
    }
    int orow = (2 * h) * 516 + 2 * w;
    hf[orow]       = v[0];
    hf[orow + 1]   = v[1];
    hf[orow + 516] = v[2];
    hf[orow + 517] = v[3];
}

// ------- K3: 5x5 separable gaussian blur (reflect) + per-block partials -----
__global__ __launch_bounds__(256) void k_blur(const float* __restrict__ hf,
                                              float* __restrict__ hfb,
                                              float* __restrict__ psum,
                                              float* __restrict__ pmax,
                                              float g0, float g1, float g2)
{
    __shared__ float ss[256], sm[256];
    int t = threadIdx.x;
    int idx = blockIdx.x * 256 + t;
    bool ok = idx < 516 * 516;
    int idc = ok ? idx : 0;
    int y = idc / 516, x = idc - y * 516;
    float g[5] = {g0, g1, g2, g1, g0};
    int ry[5], rx[5];
#pragma unroll
    for (int i = 0; i < 5; ++i) {
        int yy = y + i - 2; yy = yy < 0 ? -yy : (yy > 515 ? 1030 - yy : yy);
        int xx = x + i - 2; xx = xx < 0 ? -xx : (xx > 515 ? 1030 - xx : xx);
        ry[i] = yy * 516; rx[i] = xx;
    }
    float s = 0.f;
#pragma unroll
    for (int i = 0; i < 5; ++i) {
        float rs = 0.f;
#pragma unroll
        for (int j = 0; j < 5; ++j) rs = fmaf(g[j], hf[ry[i] + rx[j]], rs);
        s = fmaf(g[i], rs, s);
    }
    if (ok) hfb[idx] = s;

    ss[t] = ok ? s : 0.f;
    sm[t] = ok ? s : -3.4e38f;
    __syncthreads();
    for (int off = 128; off > 0; off >>= 1) {
        if (t < off) { ss[t] += ss[t + off]; sm[t] = fmaxf(sm[t], sm[t + off]); }
        __syncthreads();
    }
    if (t == 0) { psum[blockIdx.x] = ss[0]; pmax[blockIdx.x] = sm[0]; }
}

// --- K5: final reduce -> sigmoid gate + 6x6 valid conv + bias+relu+residual -
__global__ __launch_bounds__(256) void k_cat(const float* __restrict__ hfb,
                                             const float* __restrict__ tmp12,
                                             const float* __restrict__ psum,
                                             const float* __restrict__ pmax,
                                             const float* __restrict__ caw1,
                                             const float* __restrict__ caw2,
                                             const float* __restrict__ w_cat,
                                             const float* __restrict__ b_cat,
                                             float* __restrict__ f12)
{
    __shared__ float ss[256], sm[256], ssc;
    int t = threadIdx.x;
    {   // redundant per-block reduce of the 1041 partials (deterministic)
        float s = 0.f, m = -3.4e38f;
        for (int i = t; i < NBLUR; i += 256) { s += psum[i]; m = fmaxf(m, pmax[i]); }
        ss[t] = s; sm[t] = m;
        __syncthreads();
        for (int off = 128; off > 0; off >>= 1) {
            if (t < off) { ss[t] += ss[t + off]; sm[t] = fmaxf(sm[t], sm[t + off]); }
            __syncthreads();
        }
        if (t == 0) {
            float avg = ss[0] / 266256.f;
            float a = caw1[0], b = caw2[0];
            float z = b * fmaxf(a * avg, 0.f) + b * fmaxf(a * sm[0], 0.f);
            ssc = 1.f / (1.f + expf(-z));
        }
        __syncthreads();
    }
    float sc = ssc;

    int p = blockIdx.x * 256 + t;
    if (p >= NP) return;
    int y = p / 511, x = p - y * 511;
    float s = 0.f;
#pragma unroll
    for (int ky = 0; ky < 6; ++ky) {
        const float* row = hfb + (y + ky) * 516 + x;
#pragma unroll
        for (int kx = 0; kx < 6; ++kx) s = fmaf(row[kx], w_cat[ky * 6 + kx], s);
    }
    f12[p] = tmp12[p] + fmaxf(sc * s + b_cat[0], 0.f);
}

// ---------------- K6: 3x3 conv 1->32, pad 1, relu -> bf16 4-plane h2 --------
__global__ __launch_bounds__(256) void k_c9a(const float* __restrict__ f12,
                                             const float* __restrict__ wTa,
                                             const float* __restrict__ bias,
                                             unsigned short* __restrict__ h2)
{
    int p = blockIdx.x * 256 + threadIdx.x;
    if (p >= NP) return;
    int y = p / 511, x = p - y * 511;
    float hv[9];
#pragma unroll
    for (int ky = 0; ky < 3; ++ky)
#pragma unroll
        for (int kx = 0; kx < 3; ++kx) {
            int yy = y + ky - 1, xx = x + kx - 1;
            hv[ky * 3 + kx] = (yy >= 0 && yy < 511 && xx >= 0 && xx < 511) ? f12[yy * 511 + xx] : 0.f;
        }
    float acc[32];
#pragma unroll
    for (int o = 0; o < 32; ++o) acc[o] = bias[o];
#pragma unroll
    for (int k = 0; k < 9; ++k) {
        float v = hv[k];
        const float* wp = wTa + k * 32;
#pragma unroll
        for (int o = 0; o < 32; ++o) acc[o] = fmaf(v, wp[o], acc[o]);
    }
    unsigned short o16[32];
#pragma unroll
    for (int o = 0; o < 32; ++o) o16[o] = f2bf(fmaxf(acc[o], 0.f));
    size_t px = (size_t)(y + 1) * WPX + (x + 1);
#pragma unroll
    for (int i = 0; i < 4; ++i)
        *reinterpret_cast<short8*>(h2 + (size_t)i * PSTR + px * 8) =
            reinterpret_cast<const short8*>(o16)[i];
}

// ---------------- K7: 3x3 conv 32->64, MFMA, LDS weights, 2-ahead pipeline --
__global__ __launch_bounds__(256, 3) void k_c9b(const unsigned short* __restrict__ h2,
                                                const unsigned short* __restrict__ wb2,
                                                const float* __restrict__ bias,
                                                float* __restrict__ out)
{
    __shared__ unsigned short swu[9 * 2048];   // [kt][m][lane][8ch] lane-linear

    int bid = blockIdx.x;
    int xcd = bid & 7, jj = bid >> 3;
    const int q = 127, r = 6;
    int wg = (xcd < r ? xcd * (q + 1) : r * (q + 1) + (xcd - r) * q) + jj;

    int lane = threadIdx.x & 63;
    int wave = threadIdx.x >> 6;
    int y  = wg >> 1;
    int xh = wg & 1;
    int xb = xh * 256 + wave * 64;
    int lpx = lane & 15, kg = lane >> 4;

    // stage weights: dst short8 d = kt*256 + m*64 + l  <-  src kt*256+(m*16+(l&15))*4+(l>>4)
    {
        const short8* wsrc = reinterpret_cast<const short8*>(wb2);
        short8* wdst = reinterpret_cast<short8*>(swu);
        for (int d = threadIdx.x; d < 2304; d += 256) {
            int kt = d >> 8, rem = d & 255, m = rem >> 6, l = rem & 63;
            wdst[d] = wsrc[kt * 256 + (m * 16 + (l & 15)) * 4 + (l >> 4)];
        }
    }
    __syncthreads();

    f32x4 acc[4][4];
#pragma unroll
    for (int m = 0; m < 4; ++m)
#pragma unroll
        for (int n = 0; n < 4; ++n) acc[m][n] = (f32x4){0.f, 0.f, 0.f, 0.f};

    const unsigned short* hb = h2 + (size_t)kg * PSTR;
    const int base_px = (y + 1) * WPX + (xb + 1) + lpx;
    const int rowm = base_px - WPX, row0 = base_px, rowp = base_px + WPX;
    const short8* swv = reinterpret_cast<const short8*>(swu);

#define LOADB(BUF, ROW, DX) do { \
        const unsigned short* rp = hb + (size_t)((ROW) + (DX)) * 8; \
        BUF[0] = *reinterpret_cast<const short8*>(rp); \
        BUF[1] = *reinterpret_cast<const short8*>(rp + 128); \
        BUF[2] = *reinterpret_cast<const short8*>(rp + 256); \
        BUF[3] = *reinterpret_cast<const short8*>(rp + 384); \
    } while (0)

#define TAP(KT, BUF) do { \
        const short8* ap = swv + (KT) * 256 + lane; \
        short8 a0 = ap[0], a1 = ap[64], a2 = ap[128], a3 = ap[192]; \
        _Pragma("unroll") \
        for (int n = 0; n < 4; ++n) { \
            acc[0][n] = __builtin_amdgcn_mfma_f32_16x16x32_bf16(a0, BUF[n], acc[0][n], 0, 0, 0); \
            acc[1][n] = __builtin_amdgcn_mfma_f32_16x16x32_bf16(a1, BUF[n], acc[1][n], 0, 0, 0); \
            acc[2][n] = __builtin_amdgcn_mfma_f32_16x16x32_bf16(a2, BUF[n], acc[2][n], 0, 0, 0); \
            acc[3][n] = __builtin_amdgcn_mfma_f32_16x16x32_bf16(a3, BUF[n], acc[3][n], 0, 0, 0); \
        } \
    } while (0)

    short8 bX[4], bY[4], bZ[4];
    LOADB(bX, rowm, -1);
    LOADB(bY, rowm,  0);
    LOADB(bZ, rowm, +1); TAP(0, bX);
    LOADB(bX, row0, -1); TAP(1, bY);
    LOADB(bY, row0,  0); TAP(2, bZ);
    LOADB(bZ, row0, +1); TAP(3, bX);
    LOADB(bX, rowp, -1); TAP(4, bY);
    LOADB(bY, rowp,  0); TAP(5, bZ);
    LOADB(bZ, rowp, +1); TAP(6, bX);
    TAP(7, bY);
    TAP(8, bZ);
#undef LOADB
#undef TAP

    const int ybase = y * 511;
#pragma unroll
    for (int m = 0; m < 4; ++m) {
#pragma unroll
        for (int rr = 0; rr < 4; ++rr) {
            int o = m * 16 + kg * 4 + rr;
            float bo = bias[o];
#pragma unroll
            for (int n = 0; n < 4; ++n) {
                int px = xb + n * 16 + lpx;
                if (px < 511)
                    out[(size_t)o * NP + ybase + px] = fmaxf(acc[m][n][rr] + bo, 0.f);
            }
        }
    }
}

// ---------------------------------------------------------------------------
extern "C" void kernel_launch(void* const* d_in, const int* in_sizes, int n_in,
                              void* d_out, int out_size, void* d_ws, size_t ws_size,
                              hipStream_t stream)
{
    (void)in_sizes; (void)n_in; (void)out_size; (void)ws_size;

    const float* x     = (const float*)d_in[0];
    const float* w_x1  = (const float*)d_in[1];
    const float* b_x1  = (const float*)d_in[2];
    const float* w_x2  = (const float*)d_in[3];
    const float* b_x2  = (const float*)d_in[4];
    const float* w_x3  = (const float*)d_in[5];
    const float* b_x3  = (const float*)d_in[6];
    const float* w_hi  = (const float*)d_in[7];
    const float* b_hi  = (const float*)d_in[8];
    const float* ca1w1 = (const float*)d_in[11];
    const float* ca1w2 = (const float*)d_in[12];
    const float* w_cat = (const float*)d_in[15];
    const float* b_cat = (const float*)d_in[16];
    const float* w_c9a = (const float*)d_in[17];
    const float* b_c9a = (const float*)d_in[18];
    const float* w_c9b = (const float*)d_in[19];
    const float* b_c9b = (const float*)d_in[20];

    float* ws    = (float*)d_ws;
    float* tmp12 = ws + 0;                       // 261184
    float* hf    = ws + 261184;                  // 266304
    float* hfb   = ws + 527488;                  // 266304
    float* f12   = ws + 793792;                  // 261184
    float* psum  = ws + 1054976;                 // 1056
    float* pmax  = ws + 1056032;                 // 1056
    float* wTa   = ws + 1057088;                 // 320
    float* wT1   = ws + 1057408;                 // 3264 -> 3328
    unsigned short* wb2 = (unsigned short*)(ws + 1060736);   // 18432 ushorts
    unsigned short* h2  = (unsigned short*)(ws + 1069952);   // 4*PSTR ushorts

    float* out = (float*)d_out;

    double kk[5], ssum = 0.0;
    for (int i = 0; i < 5; ++i) { double r = i - 2.0; kk[i] = exp(-r * r / 0.5); ssum += kk[i]; }
    float g0 = (float)(kk[0] / ssum), g1 = (float)(kk[1] / ssum), g2 = (float)(kk[2] / ssum);

    k_prep<<<72, 256, 0, stream>>>(w_c9a, w_c9b, w_x1, wTa, wb2, wT1, h2);
    k_conv123<<<256, 512, 0, stream>>>(x, wT1, b_x1, w_x2, b_x2, w_x3, b_x3, tmp12);
    k_dwt_hi<<<261, 256, 0, stream>>>(tmp12, w_hi, b_hi, hf);
    k_blur<<<NBLUR, 256, 0, stream>>>(hf, hfb, psum, pmax, g0, g1, g2);
    k_cat<<<1021, 256, 0, stream>>>(hfb, tmp12, psum, pmax, ca1w1, ca1w2, w_cat, b_cat, f12);
    k_c9a<<<1021, 256, 0, stream>>>(f12, wTa, b_c9a, h2);
    k_c9b<<<1022, 256, 0, stream>>>(h2, wb2, b_c9b, out);
}